// Round 12
// baseline (95.680 us; speedup 1.0000x reference)
//
#include <hip/hip_runtime.h>

// CompiledLogicNet fully fused, SINGLE kernel: one block per u32 batch-column
// (32 samples). State [16384] u32 (16000 padded) in LDS, double-buffered.
// Gathers = LDS reads. Raw idx_a/idx_b/neg arrays are read directly from L2
// (broadcast across blocks) one layer ahead; negation flags packed to 8 bits
// per 4-gate group in-register. No desc prep kernel, no workspace use.
// GroupSum: one wave per class, b128 reads + CSA planes + shfl_xor butterfly.
// NOTE (do not revisit): bank-balancing preps regressed (R5 +23us serial-LDS,
// R7 +8us ballot-search); cross-block pair-split regressed (R9 +73us);
// read/compute reorderings neutral (R8/R10).

#define NIN   784
#define WIDTH 16000
#define SW    16384    // padded width (16 * TPB)
#define NH    4
#define NC    10
#define GPC   1600     // gates per class
#define NBLK  128      // u32 columns: 4096 batch / 32
#define TPB   1024

typedef unsigned int u32;

// neg bits for 4 consecutive gates: u0=(na0,nb0,na1,nb1), u1=(na2,nb2,na3,nb3)
// -> na at bits 0..3, nb at bits 4..7
__device__ __forceinline__ u32 packneg(uint4 u0, uint4 u1) {
    return (u0.x & 1u) | ((u0.z & 1u) << 1) | ((u1.x & 1u) << 2) | ((u1.z & 1u) << 3)
         | ((u0.y & 1u) << 4) | ((u0.w & 1u) << 5) | ((u1.y & 1u) << 6) | ((u1.w & 1u) << 7);
}

__launch_bounds__(TPB, 4)
__global__ void net_kernel(const int* __restrict__ x,
                           const int* __restrict__ ia0, const int* __restrict__ ib0,
                           const int* __restrict__ n0,
                           const int* __restrict__ iah, const int* __restrict__ ibh,
                           const int* __restrict__ nh,
                           int* __restrict__ out) {
    __shared__ __align__(16) u32 xw[NIN];
    __shared__ __align__(16) u32 bufA[SW];
    __shared__ __align__(16) u32 bufB[SW];

    int w = blockIdx.x;
    int t = threadIdx.x;

    // ---- layer-0 index/neg prefetch (raw arrays, L2 broadcast) ----
    uint4 iac[4], ibc[4];
    u32 nmc[4];
#pragma unroll
    for (int j = 0; j < 4; ++j) {
        int gb = 4 * (t + j * TPB);
        if (gb < WIDTH) {
            iac[j] = *(const uint4*)(ia0 + gb);
            ibc[j] = *(const uint4*)(ib0 + gb);
            uint4 u0 = *(const uint4*)(n0 + 2 * gb);
            uint4 u1 = *(const uint4*)(n0 + 2 * gb + 4);
            nmc[j] = packneg(u0, u1);
        } else {
            iac[j] = uint4{0, 0, 0, 0};
            ibc[j] = uint4{0, 0, 0, 0};
            nmc[j] = 0u;
        }
    }

    // ---- pack: xw[i] bit r = x[w*32+r][i] (coalesced along i) ----
    if (t < NIN) {
        const int* base = x + (size_t)(w * 32) * NIN + t;
        u32 acc = 0;
#pragma unroll
        for (int r = 0; r < 32; ++r)
            acc |= (base[(size_t)r * NIN] != 0 ? 1u : 0u) << r;
        xw[t] = acc;
    }
    __syncthreads();

    // ---- 5 layers, ping-pong LDS; raw-index gather, next layer prefetched ----
    u32* cur = xw;
#pragma unroll
    for (int l = 0; l <= NH; ++l) {
        u32* dst = (l & 1) ? bufB : bufA;   // A,B,A,B,A -> result in bufA
        uint4 ian[4], ibn[4];
        u32 nmn[4];
        if (l < NH) {
            const int* pa = iah + (size_t)l * WIDTH;
            const int* pb = ibh + (size_t)l * WIDTH;
            const int* pn = nh + (size_t)l * WIDTH * 2;
#pragma unroll
            for (int j = 0; j < 4; ++j) {
                int gb = 4 * (t + j * TPB);
                if (gb < WIDTH) {
                    ian[j] = *(const uint4*)(pa + gb);
                    ibn[j] = *(const uint4*)(pb + gb);
                    uint4 u0 = *(const uint4*)(pn + 2 * gb);
                    uint4 u1 = *(const uint4*)(pn + 2 * gb + 4);
                    nmn[j] = packneg(u0, u1);
                } else {
                    ian[j] = uint4{0, 0, 0, 0};
                    ibn[j] = uint4{0, 0, 0, 0};
                    nmn[j] = 0u;
                }
            }
        }

        u32 av[4][4], bv[4][4];
#define READG(j) { \
        av[j][0] = cur[iac[j].x]; bv[j][0] = cur[ibc[j].x]; \
        av[j][1] = cur[iac[j].y]; bv[j][1] = cur[ibc[j].y]; \
        av[j][2] = cur[iac[j].z]; bv[j][2] = cur[ibc[j].z]; \
        av[j][3] = cur[iac[j].w]; bv[j][3] = cur[ibc[j].w]; }
#define COMPG(j) { \
        u32 nm = nmc[j]; \
        uint4 r; \
        r.x = (av[j][0] ^ (0u - (nm & 1u)))        & (bv[j][0] ^ (0u - ((nm >> 4) & 1u))); \
        r.y = (av[j][1] ^ (0u - ((nm >> 1) & 1u))) & (bv[j][1] ^ (0u - ((nm >> 5) & 1u))); \
        r.z = (av[j][2] ^ (0u - ((nm >> 2) & 1u))) & (bv[j][2] ^ (0u - ((nm >> 6) & 1u))); \
        r.w = (av[j][3] ^ (0u - ((nm >> 3) & 1u))) & (bv[j][3] ^ (0u - ((nm >> 7) & 1u))); \
        *(uint4*)(dst + 4 * (t + (j) * TPB)) = r; }

        READG(0)
        READG(1)
        READG(2)
        COMPG(0)
        READG(3)
        COMPG(1)
        COMPG(2)
        COMPG(3)
#undef READG
#undef COMPG

        __syncthreads();
#pragma unroll
        for (int j = 0; j < 4; ++j) { iac[j] = ian[j]; ibc[j] = ibn[j]; nmc[j] = nmn[j]; }
        cur = dst;
    }
    u32* res = bufA;

    // ---- GroupSum: one wave per class, CSA planes + shfl_xor butterfly ----
    int wave = t >> 6, lane = t & 63;
    if (wave < NC) {
        int c = wave;
        const u32* base = res + c * GPC;
        u32 p0 = 0, p1 = 0, p2 = 0, p3 = 0, p4 = 0;
#define CSA5(VAL) { u32 cy = (VAL); u32 s; \
        s = p0; p0 = s ^ cy; cy = s & cy; \
        s = p1; p1 = s ^ cy; cy = s & cy; \
        s = p2; p2 = s ^ cy; cy = s & cy; \
        s = p3; p3 = s ^ cy; cy = s & cy; \
        s = p4; p4 = s ^ cy; }
#pragma unroll
        for (int k = 0; k < 6; ++k) {
            uint4 v = *(const uint4*)(base + 4 * lane + 256 * k);  // b128, conflict-free
            CSA5(v.x); CSA5(v.y); CSA5(v.z); CSA5(v.w);
        }
        CSA5(base[1536 + lane]);   // 25 values per lane, fits 5 planes
#undef CSA5

        // butterfly: merge 64 lanes' plane sets; planes grow 5 -> 11
        u32 pl[11];
        pl[0] = p0; pl[1] = p1; pl[2] = p2; pl[3] = p3; pl[4] = p4;
#pragma unroll
        for (int s = 0; s < 6; ++s) {
            int np = 5 + s;
            u32 q[11];
#pragma unroll
            for (int i = 0; i < 11; ++i) if (i < np) q[i] = __shfl_xor(pl[i], 1 << s, 64);
            u32 carry = 0;
#pragma unroll
            for (int i = 0; i < 11; ++i) if (i < np) {
                u32 a = pl[i], b = q[i];
                u32 xr = a ^ b;
                pl[i] = xr ^ carry;
                carry = (a & b) | (carry & xr);
            }
            pl[np] = carry;
        }

        // every lane now holds the 11-plane vertical count over 1600 gates
        if (lane < 32) {
            int cntv = 0;
#pragma unroll
            for (int i = 0; i < 11; ++i) cntv += (int)((pl[i] >> lane) & 1u) << i;
            out[((size_t)w * 32 + lane) * NC + c] = cntv;
        }
    }
}

// ---------------------------------------------------------------------------
extern "C" void kernel_launch(void* const* d_in, const int* in_sizes, int n_in,
                              void* d_out, int out_size, void* d_ws, size_t ws_size,
                              hipStream_t stream) {
    const int* x      = (const int*)d_in[0];  // [4096,784] 0/1
    const int* idx_a0 = (const int*)d_in[1];  // [16000]
    const int* idx_b0 = (const int*)d_in[2];  // [16000]
    const int* neg0   = (const int*)d_in[3];  // [16000,2]
    const int* idx_a  = (const int*)d_in[4];  // [4,16000]
    const int* idx_b  = (const int*)d_in[5];  // [4,16000]
    const int* neg    = (const int*)d_in[6];  // [4,16000,2]
    int* out = (int*)d_out;                   // [4096,10]

    net_kernel<<<NBLK, TPB, 0, stream>>>(x, idx_a0, idx_b0, neg0,
                                         idx_a, idx_b, neg, out);
}